// Round 1
// baseline (321.145 us; speedup 1.0000x reference)
//
#include <hip/hip_runtime.h>

#define BB 8
#define LL 1024
#define DIN 256
#define DM 512
#define HH 8
#define DH 64

typedef __attribute__((ext_vector_type(8))) short bf16x8;
typedef __attribute__((ext_vector_type(4))) float f32x4;

__device__ __forceinline__ unsigned short f2bf(float f) {
  union { float f; unsigned u; } c; c.f = f;
  unsigned u = c.u;
  return (unsigned short)((u + 0x7fffu + ((u >> 16) & 1u)) >> 16);
}

// ---------------- K1: QKV projection ----------------
// grid (8 = head/ntile, 64 = mtile, 3 = tensor), block 256 (4 waves)
// Q,K -> (B,H,L,64) bf16 ; V -> (B,H,64,L) bf16 (transposed for PV B-frags)
__global__ __launch_bounds__(256) void qkv_proj(
    const float* __restrict__ qin, const float* __restrict__ kin,
    const float* __restrict__ vin,
    const float* __restrict__ wq, const float* __restrict__ wk,
    const float* __restrict__ wv,
    unsigned short* __restrict__ qb, unsigned short* __restrict__ kb,
    unsigned short* __restrict__ vt)
{
  const int t = blockIdx.z;
  const float* __restrict__ X = (t == 0) ? qin : (t == 1) ? kin : vin;
  const float* __restrict__ W = (t == 0) ? wq : (t == 1) ? wk : wv;
  const int m0 = blockIdx.y * 128;
  const int h  = blockIdx.x;  // n0 = h*64 : one head per n-tile
  __shared__ unsigned short As[128 * 40];  // pad 40 breaks pow2 stride
  __shared__ unsigned short Bs[64 * 40];
  const int tid = threadIdx.x;
  const int wid = tid >> 6;
  const int lane = tid & 63;
  const int lo = lane & 15;
  const int quad = lane >> 4;

  f32x4 acc[2][4];
#pragma unroll
  for (int mi = 0; mi < 2; ++mi)
#pragma unroll
    for (int ni = 0; ni < 4; ++ni) acc[mi][ni] = (f32x4)0.0f;

  for (int kk = 0; kk < DIN; kk += 32) {
    // stage A: 128x32 fp32 -> bf16 LDS (coalesced float4)
#pragma unroll
    for (int i = 0; i < 4; ++i) {
      int id = i * 256 + tid;
      int row = id >> 3, ch = id & 7;
      float4 v = *(const float4*)&X[(m0 + row) * DIN + kk + ch * 4];
      ushort4 o = { f2bf(v.x), f2bf(v.y), f2bf(v.z), f2bf(v.w) };
      *(ushort4*)&As[row * 40 + ch * 4] = o;
    }
    // stage B: W[n][k] rows (B-frag layout = row n, contiguous k)
#pragma unroll
    for (int i = 0; i < 2; ++i) {
      int id = i * 256 + tid;
      int row = id >> 3, ch = id & 7;
      float4 v = *(const float4*)&W[(h * 64 + row) * DIN + kk + ch * 4];
      ushort4 o = { f2bf(v.x), f2bf(v.y), f2bf(v.z), f2bf(v.w) };
      *(ushort4*)&Bs[row * 40 + ch * 4] = o;
    }
    __syncthreads();
    bf16x8 a[2], bfr[4];
#pragma unroll
    for (int mi = 0; mi < 2; ++mi)
      a[mi] = *(const bf16x8*)&As[(wid * 32 + mi * 16 + lo) * 40 + quad * 8];
#pragma unroll
    for (int ni = 0; ni < 4; ++ni)
      bfr[ni] = *(const bf16x8*)&Bs[(ni * 16 + lo) * 40 + quad * 8];
#pragma unroll
    for (int mi = 0; mi < 2; ++mi)
#pragma unroll
      for (int ni = 0; ni < 4; ++ni)
        acc[mi][ni] = __builtin_amdgcn_mfma_f32_16x16x32_bf16(
            a[mi], bfr[ni], acc[mi][ni], 0, 0, 0);
    __syncthreads();
  }

  // epilogue: C layout row = quad*4+r, col = lo
  const int b = m0 >> 10;
  const int lbase0 = (m0 & 1023) + wid * 32;
  if (t < 2) {
    unsigned short* dstp = (t == 0) ? qb : kb;
#pragma unroll
    for (int mi = 0; mi < 2; ++mi)
#pragma unroll
      for (int ni = 0; ni < 4; ++ni) {
        int d = ni * 16 + lo;
#pragma unroll
        for (int r = 0; r < 4; ++r) {
          int lb = lbase0 + mi * 16 + quad * 4 + r;
          dstp[((b * HH + h) * LL + lb) * DH + d] = f2bf(acc[mi][ni][r]);
        }
      }
  } else {  // V transposed: lane's 4 regs are consecutive l -> one 8B store
#pragma unroll
    for (int mi = 0; mi < 2; ++mi)
#pragma unroll
      for (int ni = 0; ni < 4; ++ni) {
        int d = ni * 16 + lo;
        int lb = lbase0 + mi * 16 + quad * 4;
        ushort4 o = { f2bf(acc[mi][ni][0]), f2bf(acc[mi][ni][1]),
                      f2bf(acc[mi][ni][2]), f2bf(acc[mi][ni][3]) };
        *(ushort4*)&vt[((b * HH + h) * DH + d) * LL + lb] = o;
      }
  }
}

// ---------------- K2: fused biased flash attention ----------------
// grid (32 = qtile, 8 = b), block 512 (8 waves = 8 heads).
// Bias tiles (adj/dist) staged once per block, shared across all heads.
__global__ __launch_bounds__(512) void attn(
    const unsigned short* __restrict__ qb, const unsigned short* __restrict__ kb,
    const unsigned short* __restrict__ vt,
    const int* __restrict__ msk,
    const float* __restrict__ adj, const float* __restrict__ dis,
    const float* __restrict__ la_, const float* __restrict__ ld_,
    unsigned short* __restrict__ ao)
{
  const int b = blockIdx.y;
  const int q0 = blockIdx.x * 32;
  const int tid = threadIdx.x;
  const int h = tid >> 6;     // wave = head
  const int lane = tid & 63;
  const int lo = lane & 15;
  const int quad = lane >> 4;

  __shared__ float adjb[32 * 36];   // pad 36: 2-way conflicts only (free)
  __shared__ float disb[32 * 36];
  __shared__ int maskb[32];
  __shared__ unsigned short pbuf[HH][32 * 40];  // per-wave P round-trip

  const float la = la_[h];
  const float ld = ld_[h];

  // Q fragments in registers (A-layout: m=lo, k=quad*8+j)
  const unsigned short* qp = qb + ((size_t)(b * HH + h) * LL + q0) * DH;
  bf16x8 qf[2][2];
#pragma unroll
  for (int mi = 0; mi < 2; ++mi)
#pragma unroll
    for (int ki = 0; ki < 2; ++ki)
      qf[mi][ki] = *(const bf16x8*)&qp[(mi * 16 + lo) * DH + ki * 32 + quad * 8];

  const unsigned short* kp = kb + (size_t)(b * HH + h) * LL * DH;
  const unsigned short* vp = vt + (size_t)(b * HH + h) * DH * LL;

  f32x4 o[2][4];
  float mrow[2][4], lrow[2][4];
#pragma unroll
  for (int mi = 0; mi < 2; ++mi) {
#pragma unroll
    for (int ni = 0; ni < 4; ++ni) o[mi][ni] = (f32x4)0.0f;
#pragma unroll
    for (int r = 0; r < 4; ++r) { mrow[mi][r] = -1e30f; lrow[mi][r] = 0.0f; }
  }

  for (int k0 = 0; k0 < LL; k0 += 32) {
    // K/V fragments direct from global (L2/L3-resident), issued early
    bf16x8 kf[2][2], vf[4];
#pragma unroll
    for (int ni = 0; ni < 2; ++ni)
#pragma unroll
      for (int ki = 0; ki < 2; ++ki)
        kf[ni][ki] = *(const bf16x8*)&kp[(k0 + ni * 16 + lo) * DH + ki * 32 + quad * 8];
#pragma unroll
    for (int ni = 0; ni < 4; ++ni)
      vf[ni] = *(const bf16x8*)&vp[(ni * 16 + lo) * LL + k0 + quad * 8];

    // stage bias tiles: waves 0-3 adj, waves 4-7 dist
    if (tid < 256) {
      int row = tid >> 3, ch = tid & 7;
      float4 v = *(const float4*)&adj[((size_t)b * LL + q0 + row) * LL + k0 + ch * 4];
      *(float4*)&adjb[row * 36 + ch * 4] = v;
    } else {
      int id2 = tid - 256;
      int row = id2 >> 3, ch = id2 & 7;
      float4 v = *(const float4*)&dis[((size_t)b * LL + q0 + row) * LL + k0 + ch * 4];
      *(float4*)&disb[row * 36 + ch * 4] = v;
    }
    if (tid < 32) maskb[tid] = msk[b * LL + k0 + tid];
    __syncthreads();

    // S = Q K^T  (32x32 tile)
    f32x4 s[2][2];
#pragma unroll
    for (int mi = 0; mi < 2; ++mi)
#pragma unroll
      for (int ni = 0; ni < 2; ++ni) s[mi][ni] = (f32x4)0.0f;
#pragma unroll
    for (int ki = 0; ki < 2; ++ki)
#pragma unroll
      for (int ni = 0; ni < 2; ++ni) {
        s[0][ni] = __builtin_amdgcn_mfma_f32_16x16x32_bf16(qf[0][ki], kf[ni][ki], s[0][ni], 0, 0, 0);
        s[1][ni] = __builtin_amdgcn_mfma_f32_16x16x32_bf16(qf[1][ki], kf[ni][ki], s[1][ni], 0, 0, 0);
      }

    // scale + bias + mask + online softmax (C layout: row=quad*4+r, col=lo)
#pragma unroll
    for (int mi = 0; mi < 2; ++mi) {
      float tmax[4], rs[4], al[4];
#pragma unroll
      for (int ni = 0; ni < 2; ++ni) {
        int kc = ni * 16 + lo;
        bool dead = (maskb[kc] == 0);
#pragma unroll
        for (int r = 0; r < 4; ++r) {
          int qr = mi * 16 + quad * 4 + r;
          float v = s[mi][ni][r] * 0.125f + la * adjb[qr * 36 + kc] + ld * disb[qr * 36 + kc];
          s[mi][ni][r] = dead ? -1e9f : v;
        }
      }
#pragma unroll
      for (int r = 0; r < 4; ++r) tmax[r] = fmaxf(s[mi][0][r], s[mi][1][r]);
#pragma unroll
      for (int m = 1; m < 16; m <<= 1)
#pragma unroll
        for (int r = 0; r < 4; ++r) tmax[r] = fmaxf(tmax[r], __shfl_xor(tmax[r], m, 16));
#pragma unroll
      for (int r = 0; r < 4; ++r) {
        float mn = fmaxf(mrow[mi][r], tmax[r]);
        al[r] = __expf(mrow[mi][r] - mn);
        mrow[mi][r] = mn;
        rs[r] = 0.0f;
      }
#pragma unroll
      for (int ni = 0; ni < 2; ++ni)
#pragma unroll
        for (int r = 0; r < 4; ++r) {
          float p = __expf(s[mi][ni][r] - mrow[mi][r]);
          s[mi][ni][r] = p;
          rs[r] += p;
        }
#pragma unroll
      for (int m = 1; m < 16; m <<= 1)
#pragma unroll
        for (int r = 0; r < 4; ++r) rs[r] += __shfl_xor(rs[r], m, 16);
#pragma unroll
      for (int r = 0; r < 4; ++r) lrow[mi][r] = lrow[mi][r] * al[r] + rs[r];
#pragma unroll
      for (int ni = 0; ni < 4; ++ni)
#pragma unroll
        for (int r = 0; r < 4; ++r) o[mi][ni][r] *= al[r];
      // P -> LDS (C layout write), for A-layout reread
#pragma unroll
      for (int ni = 0; ni < 2; ++ni)
#pragma unroll
        for (int r = 0; r < 4; ++r)
          pbuf[h][(mi * 16 + quad * 4 + r) * 40 + ni * 16 + lo] = f2bf(s[mi][ni][r]);
    }

    // per-wave LDS write->read: drain lgkm, fence compiler reordering
    asm volatile("s_waitcnt lgkmcnt(0)" ::: "memory");

    bf16x8 pf[2];
#pragma unroll
    for (int mi = 0; mi < 2; ++mi)
      pf[mi] = *(const bf16x8*)&pbuf[h][(mi * 16 + lo) * 40 + quad * 8];
#pragma unroll
    for (int ni = 0; ni < 4; ++ni) {
      o[0][ni] = __builtin_amdgcn_mfma_f32_16x16x32_bf16(pf[0], vf[ni], o[0][ni], 0, 0, 0);
      o[1][ni] = __builtin_amdgcn_mfma_f32_16x16x32_bf16(pf[1], vf[ni], o[1][ni], 0, 0, 0);
    }
    __syncthreads();  // bias LDS reused next iter
  }

  // epilogue: merge heads -> (B, L, 512) bf16
#pragma unroll
  for (int mi = 0; mi < 2; ++mi)
#pragma unroll
    for (int ni = 0; ni < 4; ++ni)
#pragma unroll
      for (int r = 0; r < 4; ++r) {
        int l = q0 + mi * 16 + quad * 4 + r;
        ao[((size_t)b * LL + l) * DM + h * DH + ni * 16 + lo] =
            f2bf(o[mi][ni][r] / lrow[mi][r]);
      }
}

// ---------------- K3: output projection ----------------
// grid (8 ntile, 64 mtile), block 256
__global__ __launch_bounds__(256) void oproj(
    const unsigned short* __restrict__ ao, const float* __restrict__ wo,
    float* __restrict__ out)
{
  const int m0 = blockIdx.y * 128;
  const int n0 = blockIdx.x * 64;
  __shared__ unsigned short As[128 * 40];
  __shared__ unsigned short Bs[64 * 40];
  const int tid = threadIdx.x;
  const int wid = tid >> 6;
  const int lane = tid & 63;
  const int lo = lane & 15;
  const int quad = lane >> 4;

  f32x4 acc[2][4];
#pragma unroll
  for (int mi = 0; mi < 2; ++mi)
#pragma unroll
    for (int ni = 0; ni < 4; ++ni) acc[mi][ni] = (f32x4)0.0f;

  for (int kk = 0; kk < DM; kk += 32) {
    // stage A: already bf16, 16B copies
#pragma unroll
    for (int i = 0; i < 2; ++i) {
      int id = i * 256 + tid;
      int row = id >> 2, ch = id & 3;
      uint4 v = *(const uint4*)&ao[(size_t)(m0 + row) * DM + kk + ch * 8];
      *(uint4*)&As[row * 40 + ch * 8] = v;
    }
#pragma unroll
    for (int i = 0; i < 2; ++i) {
      int id = i * 256 + tid;
      int row = id >> 3, ch = id & 7;
      float4 v = *(const float4*)&wo[(n0 + row) * DM + kk + ch * 4];
      ushort4 o = { f2bf(v.x), f2bf(v.y), f2bf(v.z), f2bf(v.w) };
      *(ushort4*)&Bs[row * 40 + ch * 4] = o;
    }
    __syncthreads();
    bf16x8 a[2], bfr[4];
#pragma unroll
    for (int mi = 0; mi < 2; ++mi)
      a[mi] = *(const bf16x8*)&As[(wid * 32 + mi * 16 + lo) * 40 + quad * 8];
#pragma unroll
    for (int ni = 0; ni < 4; ++ni)
      bfr[ni] = *(const bf16x8*)&Bs[(ni * 16 + lo) * 40 + quad * 8];
#pragma unroll
    for (int mi = 0; mi < 2; ++mi)
#pragma unroll
      for (int ni = 0; ni < 4; ++ni)
        acc[mi][ni] = __builtin_amdgcn_mfma_f32_16x16x32_bf16(
            a[mi], bfr[ni], acc[mi][ni], 0, 0, 0);
    __syncthreads();
  }

#pragma unroll
  for (int mi = 0; mi < 2; ++mi)
#pragma unroll
    for (int ni = 0; ni < 4; ++ni)
#pragma unroll
      for (int r = 0; r < 4; ++r)
        out[(size_t)(m0 + wid * 32 + mi * 16 + quad * 4 + r) * DM +
            n0 + ni * 16 + lo] = acc[mi][ni][r];
}

extern "C" void kernel_launch(void* const* d_in, const int* in_sizes, int n_in,
                              void* d_out, int out_size, void* d_ws, size_t ws_size,
                              hipStream_t stream) {
  const float* qin = (const float*)d_in[0];
  const float* kin = (const float*)d_in[1];
  const float* vin = (const float*)d_in[2];
  const int*   msk = (const int*)d_in[3];
  const float* adj = (const float*)d_in[4];
  const float* dis = (const float*)d_in[5];
  const float* wq  = (const float*)d_in[6];
  const float* wk  = (const float*)d_in[7];
  const float* wv  = (const float*)d_in[8];
  const float* wo  = (const float*)d_in[9];
  const float* la  = (const float*)d_in[10];
  const float* ld  = (const float*)d_in[11];
  float* out = (float*)d_out;

  const size_t tensb = (size_t)BB * HH * LL * DH;  // elems per bf16 tensor
  unsigned short* qb = (unsigned short*)d_ws;
  unsigned short* kb = qb + tensb;
  unsigned short* vt = kb + tensb;
  unsigned short* ao = vt + tensb;  // (B, L, 512) merged-heads bf16

  qkv_proj<<<dim3(8, 64, 3), 256, 0, stream>>>(qin, kin, vin, wq, wk, wv, qb, kb, vt);
  attn<<<dim3(32, 8), 512, 0, stream>>>(qb, kb, vt, msk, adj, dis, la, ld, ao);
  oproj<<<dim3(8, 64), 256, 0, stream>>>(ao, wo, out);
}

// Round 2
// 289.610 us; speedup vs baseline: 1.1089x; 1.1089x over previous
//
#include <hip/hip_runtime.h>

#define BB 8
#define LL 1024
#define DIN 256
#define DM 512
#define HH 8
#define DH 64

typedef __attribute__((ext_vector_type(8))) short bf16x8;
typedef __attribute__((ext_vector_type(4))) float f32x4;
typedef __attribute__((ext_vector_type(4))) int i32x4;

__device__ __forceinline__ unsigned short f2bf(float f) {
  union { float f; unsigned u; } c; c.f = f;
  unsigned u = c.u;
  return (unsigned short)((u + 0x7fffu + ((u >> 16) & 1u)) >> 16);
}

// ---------------- K0a: X fp32 -> bf16 precast ----------------
__global__ __launch_bounds__(256) void conv_x(
    const float* __restrict__ q, const float* __restrict__ k,
    const float* __restrict__ v,
    unsigned short* __restrict__ xq, unsigned short* __restrict__ xk,
    unsigned short* __restrict__ xv)
{
  const float* src = (blockIdx.y == 0) ? q : (blockIdx.y == 1) ? k : v;
  unsigned short* dst = (blockIdx.y == 0) ? xq : (blockIdx.y == 1) ? xk : xv;
  int i = (blockIdx.x * 256 + threadIdx.x) * 4;
  float4 f = *(const float4*)&src[i];
  ushort4 o = { f2bf(f.x), f2bf(f.y), f2bf(f.z), f2bf(f.w) };
  *(ushort4*)&dst[i] = o;
}

// ---------------- K0b: W fp32 -> bf16 precast ----------------
__global__ __launch_bounds__(256) void conv_w(
    const float* __restrict__ wq, const float* __restrict__ wk,
    const float* __restrict__ wv, const float* __restrict__ wo,
    unsigned short* __restrict__ wqb, unsigned short* __restrict__ wkb,
    unsigned short* __restrict__ wvb, unsigned short* __restrict__ wob)
{
  const int z = blockIdx.y;
  const float* src = (z == 0) ? wq : (z == 1) ? wk : (z == 2) ? wv
                     : (z == 3) ? wo : wo + 131072;
  unsigned short* dst = (z == 0) ? wqb : (z == 1) ? wkb : (z == 2) ? wvb
                        : (z == 3) ? wob : wob + 131072;
  int i = (blockIdx.x * 256 + threadIdx.x) * 4;
  float4 f = *(const float4*)&src[i];
  ushort4 o = { f2bf(f.x), f2bf(f.y), f2bf(f.z), f2bf(f.w) };
  *(ushort4*)&dst[i] = o;
}

// ---------------- K1: QKV projection (bf16 in, bf16 out) ----------------
// grid (8 = head/ntile, 64 = mtile, 3 = tensor), block 256 (4 waves)
// Q,K -> (B,H,L,64) ; V -> (B,H,64,L) transposed
__global__ __launch_bounds__(256) void qkv_proj(
    const unsigned short* __restrict__ xq, const unsigned short* __restrict__ xk,
    const unsigned short* __restrict__ xv,
    const unsigned short* __restrict__ wqb, const unsigned short* __restrict__ wkb,
    const unsigned short* __restrict__ wvb,
    unsigned short* __restrict__ qb, unsigned short* __restrict__ kb,
    unsigned short* __restrict__ vt)
{
  const int t = blockIdx.z;
  const unsigned short* __restrict__ X = (t == 0) ? xq : (t == 1) ? xk : xv;
  const unsigned short* __restrict__ W = (t == 0) ? wqb : (t == 1) ? wkb : wvb;
  const int m0 = blockIdx.y * 128;
  const int h  = blockIdx.x;
  __shared__ unsigned short As[128 * 40];
  __shared__ unsigned short Bs[64 * 40];
  const int tid = threadIdx.x;
  const int wid = tid >> 6;
  const int lane = tid & 63;
  const int lo = lane & 15;
  const int quad = lane >> 4;

  f32x4 acc[2][4];
#pragma unroll
  for (int mi = 0; mi < 2; ++mi)
#pragma unroll
    for (int ni = 0; ni < 4; ++ni) acc[mi][ni] = (f32x4)0.0f;

  for (int kk = 0; kk < DIN; kk += 32) {
#pragma unroll
    for (int i = 0; i < 2; ++i) {
      int id = i * 256 + tid;
      int row = id >> 2, ch = id & 3;
      *(uint4*)&As[row * 40 + ch * 8] =
          *(const uint4*)&X[(size_t)(m0 + row) * DIN + kk + ch * 8];
    }
    {
      int row = tid >> 2, ch = tid & 3;
      *(uint4*)&Bs[row * 40 + ch * 8] =
          *(const uint4*)&W[(size_t)(h * 64 + row) * DIN + kk + ch * 8];
    }
    __syncthreads();
    bf16x8 a[2], bfr[4];
#pragma unroll
    for (int mi = 0; mi < 2; ++mi)
      a[mi] = *(const bf16x8*)&As[(wid * 32 + mi * 16 + lo) * 40 + quad * 8];
#pragma unroll
    for (int ni = 0; ni < 4; ++ni)
      bfr[ni] = *(const bf16x8*)&Bs[(ni * 16 + lo) * 40 + quad * 8];
#pragma unroll
    for (int mi = 0; mi < 2; ++mi)
#pragma unroll
      for (int ni = 0; ni < 4; ++ni)
        acc[mi][ni] = __builtin_amdgcn_mfma_f32_16x16x32_bf16(
            a[mi], bfr[ni], acc[mi][ni], 0, 0, 0);
    __syncthreads();
  }

  const int b = m0 >> 10;
  const int lbase0 = (m0 & 1023) + wid * 32;
  if (t < 2) {
    unsigned short* dstp = (t == 0) ? qb : kb;
#pragma unroll
    for (int mi = 0; mi < 2; ++mi)
#pragma unroll
      for (int ni = 0; ni < 4; ++ni) {
        int d = ni * 16 + lo;
#pragma unroll
        for (int r = 0; r < 4; ++r) {
          int lb = lbase0 + mi * 16 + quad * 4 + r;
          dstp[((size_t)(b * HH + h) * LL + lb) * DH + d] = f2bf(acc[mi][ni][r]);
        }
      }
  } else {
#pragma unroll
    for (int mi = 0; mi < 2; ++mi)
#pragma unroll
      for (int ni = 0; ni < 4; ++ni) {
        int d = ni * 16 + lo;
        int lb = lbase0 + mi * 16 + quad * 4;
        ushort4 o = { f2bf(acc[mi][ni][0]), f2bf(acc[mi][ni][1]),
                      f2bf(acc[mi][ni][2]), f2bf(acc[mi][ni][3]) };
        *(ushort4*)&vt[((size_t)(b * HH + h) * DH + d) * LL + lb] = o;
      }
  }
}

// ---------------- K2: fused biased attention, transposed, barrier-free ----
// grid (32 qtile, 4 headgrp, 8 b), block 256 = 4 waves.
// wave -> (h = hg*2 + (wid&1), K-half = wid>>1). No per-iter barriers.
// S^T = K Q^T so C-layout row = k (contiguous quad*4+r) -> float4 bias loads.
// No-max softmax (scores bounded ~|9|): p = exp(s), deferred sum reduction.
__global__ __launch_bounds__(256) void attn(
    const unsigned short* __restrict__ qb, const unsigned short* __restrict__ kb,
    const unsigned short* __restrict__ vt,
    const int* __restrict__ msk,
    const float* __restrict__ adj, const float* __restrict__ dis,
    const float* __restrict__ la_, const float* __restrict__ ld_,
    unsigned short* __restrict__ ao)
{
  const int b = blockIdx.z;
  const int q0 = blockIdx.x * 32;
  const int hg = blockIdx.y;
  const int tid = threadIdx.x;
  const int wid = tid >> 6;
  const int lane = tid & 63;
  const int lo = lane & 15;
  const int quad = lane >> 4;
  const int h  = hg * 2 + (wid & 1);
  const int kh = wid >> 1;
  const int bh = b * HH + h;

  __shared__ unsigned short pbuf[4][32 * 40];
  __shared__ float mbuf[2][34 * 64];

  const float la = la_[h], ld = ld_[h];

  // Q as B-operand: B[n=q][k=d], n=lo, k=quad*8+j
  const unsigned short* qp = qb + ((size_t)bh * LL + q0) * DH;
  bf16x8 qB[2][2];
#pragma unroll
  for (int nj = 0; nj < 2; ++nj)
#pragma unroll
    for (int ki = 0; ki < 2; ++ki)
      qB[nj][ki] = *(const bf16x8*)&qp[(nj * 16 + lo) * DH + ki * 32 + quad * 8];

  const unsigned short* kp = kb + (size_t)bh * LL * DH;
  const unsigned short* vp = vt + (size_t)bh * DH * LL;
  const float* ap = adj + ((size_t)b * LL + q0) * LL;
  const float* dp = dis + ((size_t)b * LL + q0) * LL;
  const int* mp = msk + b * LL;

  f32x4 o[4][2];  // O^T acc: [d-chunk][q-chunk], row=d, col=q
  float rs[2] = {0.0f, 0.0f};
#pragma unroll
  for (int md = 0; md < 4; ++md)
#pragma unroll
    for (int nj = 0; nj < 2; ++nj) o[md][nj] = (f32x4)0.0f;

  const int kbeg = kh * (LL / 2);
  const int kend = kbeg + (LL / 2);
  for (int k0 = kbeg; k0 < kend; k0 += 32) {
    // K as A-operand: A[m=k-row][k=d]
    bf16x8 kA[2][2];
#pragma unroll
    for (int mi = 0; mi < 2; ++mi)
#pragma unroll
      for (int ki = 0; ki < 2; ++ki)
        kA[mi][ki] = *(const bf16x8*)&kp[(k0 + mi * 16 + lo) * DH + ki * 32 + quad * 8];
    // V^T as A-operand: A[m=d][k=k], from vt (B,H,64,L)
    bf16x8 vA[4];
#pragma unroll
    for (int md = 0; md < 4; ++md)
      vA[md] = *(const bf16x8*)&vp[(md * 16 + lo) * LL + k0 + quad * 8];
    // bias: float4 = 4 consecutive k at row q
    f32x4 av[2][2], dv[2][2];
#pragma unroll
    for (int mi = 0; mi < 2; ++mi)
#pragma unroll
      for (int nj = 0; nj < 2; ++nj) {
        av[mi][nj] = *(const f32x4*)&ap[(size_t)(nj * 16 + lo) * LL + k0 + mi * 16 + quad * 4];
        dv[mi][nj] = *(const f32x4*)&dp[(size_t)(nj * 16 + lo) * LL + k0 + mi * 16 + quad * 4];
      }
    i32x4 mv[2];
#pragma unroll
    for (int mi = 0; mi < 2; ++mi)
      mv[mi] = *(const i32x4*)&mp[k0 + mi * 16 + quad * 4];

    // S^T = K Q^T : C row = k (mi*16+quad*4+r), col = q (nj*16+lo)
    f32x4 s[2][2];
#pragma unroll
    for (int mi = 0; mi < 2; ++mi)
#pragma unroll
      for (int nj = 0; nj < 2; ++nj) s[mi][nj] = (f32x4)0.0f;
#pragma unroll
    for (int ki = 0; ki < 2; ++ki)
#pragma unroll
      for (int mi = 0; mi < 2; ++mi)
#pragma unroll
        for (int nj = 0; nj < 2; ++nj)
          s[mi][nj] = __builtin_amdgcn_mfma_f32_16x16x32_bf16(
              kA[mi][ki], qB[nj][ki], s[mi][nj], 0, 0, 0);

    // bias + mask + exp (no max subtraction), write P^T to per-wave LDS
#pragma unroll
    for (int mi = 0; mi < 2; ++mi)
#pragma unroll
      for (int nj = 0; nj < 2; ++nj)
#pragma unroll
        for (int r = 0; r < 4; ++r) {
          float v = s[mi][nj][r] * 0.125f + la * av[mi][nj][r] + ld * dv[mi][nj][r];
          float p = (mv[mi][r] != 0) ? __expf(v) : 0.0f;
          rs[nj] += p;
          pbuf[wid][(nj * 16 + lo) * 40 + mi * 16 + quad * 4 + r] = f2bf(p);
        }

    asm volatile("s_waitcnt lgkmcnt(0)" ::: "memory");

    // P as B-operand: B[n=q][k=k], read rows q=lo
    bf16x8 pB[2];
#pragma unroll
    for (int nj = 0; nj < 2; ++nj)
      pB[nj] = *(const bf16x8*)&pbuf[wid][(nj * 16 + lo) * 40 + quad * 8];

    // O^T += V^T P : 8 MFMAs
#pragma unroll
    for (int md = 0; md < 4; ++md)
#pragma unroll
      for (int nj = 0; nj < 2; ++nj)
        o[md][nj] = __builtin_amdgcn_mfma_f32_16x16x32_bf16(
            vA[md], pB[nj], o[md][nj], 0, 0, 0);
  }

  // merge the two K-halves (unnormalized partials just add)
  const int hs = wid & 1;
  if (kh == 1) {
#pragma unroll
    for (int md = 0; md < 4; ++md)
#pragma unroll
      for (int nj = 0; nj < 2; ++nj)
#pragma unroll
        for (int r = 0; r < 4; ++r)
          mbuf[hs][((md * 2 + nj) * 4 + r) * 64 + lane] = o[md][nj][r];
    mbuf[hs][32 * 64 + lane] = rs[0];
    mbuf[hs][33 * 64 + lane] = rs[1];
  }
  __syncthreads();
  if (kh == 0) {
#pragma unroll
    for (int md = 0; md < 4; ++md)
#pragma unroll
      for (int nj = 0; nj < 2; ++nj)
#pragma unroll
        for (int r = 0; r < 4; ++r)
          o[md][nj][r] += mbuf[hs][((md * 2 + nj) * 4 + r) * 64 + lane];
    rs[0] += mbuf[hs][32 * 64 + lane];
    rs[1] += mbuf[hs][33 * 64 + lane];
    float inv[2];
#pragma unroll
    for (int nj = 0; nj < 2; ++nj) {
      rs[nj] += __shfl_xor(rs[nj], 16);
      rs[nj] += __shfl_xor(rs[nj], 32);
      inv[nj] = 1.0f / rs[nj];
    }
    // store O^T: lane's 4 regs = consecutive d -> ushort4
#pragma unroll
    for (int md = 0; md < 4; ++md)
#pragma unroll
      for (int nj = 0; nj < 2; ++nj) {
        int l = q0 + nj * 16 + lo;
        ushort4 st = { f2bf(o[md][nj][0] * inv[nj]), f2bf(o[md][nj][1] * inv[nj]),
                       f2bf(o[md][nj][2] * inv[nj]), f2bf(o[md][nj][3] * inv[nj]) };
        *(ushort4*)&ao[((size_t)b * LL + l) * DM + h * DH + md * 16 + quad * 4] = st;
      }
  }
}

// ---------------- K3: output projection ----------------
// grid (8 ntile, 64 mtile), block 256
__global__ __launch_bounds__(256) void oproj(
    const unsigned short* __restrict__ ao, const unsigned short* __restrict__ wob,
    float* __restrict__ out)
{
  const int m0 = blockIdx.y * 128;
  const int n0 = blockIdx.x * 64;
  __shared__ unsigned short As[128 * 40];
  __shared__ unsigned short Bs[64 * 40];
  const int tid = threadIdx.x;
  const int wid = tid >> 6;
  const int lane = tid & 63;
  const int lo = lane & 15;
  const int quad = lane >> 4;

  f32x4 acc[2][4];
#pragma unroll
  for (int mi = 0; mi < 2; ++mi)
#pragma unroll
    for (int ni = 0; ni < 4; ++ni) acc[mi][ni] = (f32x4)0.0f;

  for (int kk = 0; kk < DM; kk += 32) {
#pragma unroll
    for (int i = 0; i < 2; ++i) {
      int id = i * 256 + tid;
      int row = id >> 2, ch = id & 3;
      *(uint4*)&As[row * 40 + ch * 8] =
          *(const uint4*)&ao[(size_t)(m0 + row) * DM + kk + ch * 8];
    }
    {
      int row = tid >> 2, ch = tid & 3;
      *(uint4*)&Bs[row * 40 + ch * 8] =
          *(const uint4*)&wob[(size_t)(n0 + row) * DM + kk + ch * 8];
    }
    __syncthreads();
    bf16x8 a[2], bfr[4];
#pragma unroll
    for (int mi = 0; mi < 2; ++mi)
      a[mi] = *(const bf16x8*)&As[(wid * 32 + mi * 16 + lo) * 40 + quad * 8];
#pragma unroll
    for (int ni = 0; ni < 4; ++ni)
      bfr[ni] = *(const bf16x8*)&Bs[(ni * 16 + lo) * 40 + quad * 8];
#pragma unroll
    for (int mi = 0; mi < 2; ++mi)
#pragma unroll
      for (int ni = 0; ni < 4; ++ni)
        acc[mi][ni] = __builtin_amdgcn_mfma_f32_16x16x32_bf16(
            a[mi], bfr[ni], acc[mi][ni], 0, 0, 0);
    __syncthreads();
  }

#pragma unroll
  for (int mi = 0; mi < 2; ++mi)
#pragma unroll
    for (int ni = 0; ni < 4; ++ni)
#pragma unroll
      for (int r = 0; r < 4; ++r)
        out[(size_t)(m0 + wid * 32 + mi * 16 + quad * 4 + r) * DM +
            n0 + ni * 16 + lo] = acc[mi][ni][r];
}

extern "C" void kernel_launch(void* const* d_in, const int* in_sizes, int n_in,
                              void* d_out, int out_size, void* d_ws, size_t ws_size,
                              hipStream_t stream) {
  const float* qin = (const float*)d_in[0];
  const float* kin = (const float*)d_in[1];
  const float* vin = (const float*)d_in[2];
  const int*   msk = (const int*)d_in[3];
  const float* adj = (const float*)d_in[4];
  const float* dis = (const float*)d_in[5];
  const float* wq  = (const float*)d_in[6];
  const float* wk  = (const float*)d_in[7];
  const float* wv  = (const float*)d_in[8];
  const float* wo  = (const float*)d_in[9];
  const float* la  = (const float*)d_in[10];
  const float* ld  = (const float*)d_in[11];
  float* out = (float*)d_out;

  const size_t tensb = (size_t)BB * HH * LL * DH;   // 4,194,304
  const size_t xsz   = (size_t)BB * LL * DIN;       // 2,097,152
  unsigned short* qb  = (unsigned short*)d_ws;
  unsigned short* kb  = qb + tensb;
  unsigned short* vt  = kb + tensb;
  unsigned short* ao  = vt + tensb;                 // (B,L,512) bf16
  // xq/xk alias ao (dead until attn writes it); xv + weights appended
  unsigned short* xq  = ao;
  unsigned short* xk  = ao + xsz;
  unsigned short* xv  = ao + tensb;
  unsigned short* wqb = xv + xsz;
  unsigned short* wkb = wqb + (size_t)DM * DIN;
  unsigned short* wvb = wkb + (size_t)DM * DIN;
  unsigned short* wob = wvb + (size_t)DM * DIN;

  conv_x<<<dim3(2048, 3), 256, 0, stream>>>(qin, kin, vin, xq, xk, xv);
  conv_w<<<dim3(128, 5), 256, 0, stream>>>(wq, wk, wv, wo, wqb, wkb, wvb, wob);
  qkv_proj<<<dim3(8, 64, 3), 256, 0, stream>>>(xq, xk, xv, wqb, wkb, wvb, qb, kb, vt);
  attn<<<dim3(32, 4, 8), 256, 0, stream>>>(qb, kb, vt, msk, adj, dis, la, ld, ao);
  oproj<<<dim3(8, 64), 256, 0, stream>>>(ao, wob, out);
}

// Round 3
// 288.311 us; speedup vs baseline: 1.1139x; 1.0045x over previous
//
#include <hip/hip_runtime.h>

#define BB 8
#define LL 1024
#define DIN 256
#define DM 512
#define HH 8
#define DH 64

typedef __attribute__((ext_vector_type(8))) short bf16x8;
typedef __attribute__((ext_vector_type(4))) float f32x4;
typedef __attribute__((ext_vector_type(4))) int i32x4;

__device__ __forceinline__ unsigned short f2bf(float f) {
  union { float f; unsigned u; } c; c.f = f;
  unsigned u = c.u;
  return (unsigned short)((u + 0x7fffu + ((u >> 16) & 1u)) >> 16);
}

#if defined(__has_builtin)
#if __has_builtin(__builtin_amdgcn_cvt_pk_bf16_f32)
#define HAS_PK_BF16 1
#endif
#endif

#ifdef HAS_PK_BF16
typedef __bf16 bf2 __attribute__((ext_vector_type(2)));
__device__ __forceinline__ unsigned pk2(float lo, float hi) {
  union { bf2 v; unsigned u; } c;
  c.v = __builtin_amdgcn_cvt_pk_bf16_f32(lo, hi);
  return c.u;
}
#else
__device__ __forceinline__ unsigned pk2(float lo, float hi) {
  return ((unsigned)f2bf(hi) << 16) | f2bf(lo);
}
#endif

// ---------------- K0: merged precast (X, W -> bf16; mask -> additive f32) ---
// 1D grid over float4-quads; all segment boundaries are block-aligned.
__global__ __launch_bounds__(256) void prep(
    const float* __restrict__ qin, const float* __restrict__ kin,
    const float* __restrict__ vin,
    const float* __restrict__ wq, const float* __restrict__ wk,
    const float* __restrict__ wv, const float* __restrict__ wo,
    const int* __restrict__ msk,
    unsigned short* __restrict__ xq, unsigned short* __restrict__ xk,
    unsigned short* __restrict__ xv,
    unsigned short* __restrict__ wqb, unsigned short* __restrict__ wkb,
    unsigned short* __restrict__ wvb, unsigned short* __restrict__ wob,
    float* __restrict__ mad)
{
  int t = blockIdx.x * 256 + threadIdx.x;  // quad index
  const int XS = 524288, WS = 32768;       // quads per X tensor / per W tensor
  if (t < 3 * XS) {
    int seg = t >> 19, off = t & (XS - 1);
    const float* s = (seg == 0) ? qin : (seg == 1) ? kin : vin;
    unsigned short* d = (seg == 0) ? xq : (seg == 1) ? xk : xv;
    float4 f = ((const float4*)s)[off];
    uint2 o = { pk2(f.x, f.y), pk2(f.z, f.w) };
    ((uint2*)d)[off] = o;
    return;
  }
  t -= 3 * XS;
  if (t < 3 * WS) {
    int seg = t >> 15, off = t & (WS - 1);
    const float* s = (seg == 0) ? wq : (seg == 1) ? wk : wv;
    unsigned short* d = (seg == 0) ? wqb : (seg == 1) ? wkb : wvb;
    float4 f = ((const float4*)s)[off];
    uint2 o = { pk2(f.x, f.y), pk2(f.z, f.w) };
    ((uint2*)d)[off] = o;
    return;
  }
  t -= 3 * WS;
  if (t < 65536) {
    float4 f = ((const float4*)wo)[t];
    uint2 o = { pk2(f.x, f.y), pk2(f.z, f.w) };
    ((uint2*)wob)[t] = o;
    return;
  }
  t -= 65536;  // 0..2047 : mask -> additive bias in log2 domain
  int4 m = ((const int4*)msk)[t];
  float4 f = { m.x ? 0.0f : -30000.0f, m.y ? 0.0f : -30000.0f,
               m.z ? 0.0f : -30000.0f, m.w ? 0.0f : -30000.0f };
  ((float4*)mad)[t] = f;
}

// ---------------- K1: QKV projection (bf16 in, bf16 out) ----------------
// grid (8 = head/ntile, 64 = mtile, 3 = tensor), block 256 (4 waves)
// Q,K -> (B,H,L,64) ; V -> (B,H,64,L) transposed
__global__ __launch_bounds__(256) void qkv_proj(
    const unsigned short* __restrict__ xq, const unsigned short* __restrict__ xk,
    const unsigned short* __restrict__ xv,
    const unsigned short* __restrict__ wqb, const unsigned short* __restrict__ wkb,
    const unsigned short* __restrict__ wvb,
    unsigned short* __restrict__ qb, unsigned short* __restrict__ kb,
    unsigned short* __restrict__ vt)
{
  const int t = blockIdx.z;
  const unsigned short* __restrict__ X = (t == 0) ? xq : (t == 1) ? xk : xv;
  const unsigned short* __restrict__ W = (t == 0) ? wqb : (t == 1) ? wkb : wvb;
  const int m0 = blockIdx.y * 128;
  const int h  = blockIdx.x;
  __shared__ unsigned short As[128 * 40];
  __shared__ unsigned short Bs[64 * 40];
  const int tid = threadIdx.x;
  const int wid = tid >> 6;
  const int lane = tid & 63;
  const int lo = lane & 15;
  const int quad = lane >> 4;

  f32x4 acc[2][4];
#pragma unroll
  for (int mi = 0; mi < 2; ++mi)
#pragma unroll
    for (int ni = 0; ni < 4; ++ni) acc[mi][ni] = (f32x4)0.0f;

  for (int kk = 0; kk < DIN; kk += 32) {
#pragma unroll
    for (int i = 0; i < 2; ++i) {
      int id = i * 256 + tid;
      int row = id >> 2, ch = id & 3;
      *(uint4*)&As[row * 40 + ch * 8] =
          *(const uint4*)&X[(size_t)(m0 + row) * DIN + kk + ch * 8];
    }
    {
      int row = tid >> 2, ch = tid & 3;
      *(uint4*)&Bs[row * 40 + ch * 8] =
          *(const uint4*)&W[(size_t)(h * 64 + row) * DIN + kk + ch * 8];
    }
    __syncthreads();
    bf16x8 a[2], bfr[4];
#pragma unroll
    for (int mi = 0; mi < 2; ++mi)
      a[mi] = *(const bf16x8*)&As[(wid * 32 + mi * 16 + lo) * 40 + quad * 8];
#pragma unroll
    for (int ni = 0; ni < 4; ++ni)
      bfr[ni] = *(const bf16x8*)&Bs[(ni * 16 + lo) * 40 + quad * 8];
#pragma unroll
    for (int mi = 0; mi < 2; ++mi)
#pragma unroll
      for (int ni = 0; ni < 4; ++ni)
        acc[mi][ni] = __builtin_amdgcn_mfma_f32_16x16x32_bf16(
            a[mi], bfr[ni], acc[mi][ni], 0, 0, 0);
    __syncthreads();
  }

  const int b = m0 >> 10;
  const int lbase0 = (m0 & 1023) + wid * 32;
  if (t < 2) {
    unsigned short* dstp = (t == 0) ? qb : kb;
#pragma unroll
    for (int mi = 0; mi < 2; ++mi)
#pragma unroll
      for (int ni = 0; ni < 4; ++ni) {
        int d = ni * 16 + lo;
#pragma unroll
        for (int r = 0; r < 4; ++r) {
          int lb = lbase0 + mi * 16 + quad * 4 + r;
          dstp[((size_t)(b * HH + h) * LL + lb) * DH + d] = f2bf(acc[mi][ni][r]);
        }
      }
  } else {
#pragma unroll
    for (int mi = 0; mi < 2; ++mi)
#pragma unroll
      for (int ni = 0; ni < 4; ++ni) {
        int d = ni * 16 + lo;
        int lb = lbase0 + mi * 16 + quad * 4;
        uint2 o = { pk2(acc[mi][ni][0], acc[mi][ni][1]),
                    pk2(acc[mi][ni][2], acc[mi][ni][3]) };
        *(uint2*)&vt[((size_t)(b * HH + h) * DH + d) * LL + lb] = o;
      }
  }
}

// ---------------- K2: fused biased attention, pipelined, barrier-free ----
// 1D grid 1024: idx = qt*32 + hg*8 + b  -> the 4 hg blocks of one (b,qt)
// land on the same XCD (idx%8 == b) in consecutive slots -> bias L2 reuse.
// wave -> (h = hg*2 + (wid&1), K-half = wid>>1). Loads rotated after last
// use so every global load leads its consumer by >=1 pipeline stage.
__global__ __launch_bounds__(256) void attn(
    const unsigned short* __restrict__ qb, const unsigned short* __restrict__ kb,
    const unsigned short* __restrict__ vt,
    const float* __restrict__ mad,
    const float* __restrict__ adj, const float* __restrict__ dis,
    const float* __restrict__ la_, const float* __restrict__ ld_,
    unsigned short* __restrict__ ao)
{
  const int bi = blockIdx.x;
  const int b  = bi & 7;
  const int hg = (bi >> 3) & 3;
  const int q0 = (bi >> 5) * 32;
  const int tid = threadIdx.x;
  const int wid = tid >> 6;
  const int lane = tid & 63;
  const int lo = lane & 15;
  const int quad = lane >> 4;
  const int h  = hg * 2 + (wid & 1);
  const int kh = wid >> 1;
  const int bh = b * HH + h;

  __shared__ __align__(16) unsigned short pbuf[4][32 * 40];
  __shared__ __align__(16) float mbuf[2][34 * 64];

  const float LOG2E = 1.44269504f;
  const float la2 = la_[h] * LOG2E, ld2 = ld_[h] * LOG2E;
  const float sc2 = 0.125f * LOG2E;

  // Q as B-operand: B[n=q][k=d], n=lo, k=quad*8+j
  const unsigned short* qp = qb + ((size_t)bh * LL + q0) * DH;
  bf16x8 qB[2][2];
#pragma unroll
  for (int nj = 0; nj < 2; ++nj)
#pragma unroll
    for (int ki = 0; ki < 2; ++ki)
      qB[nj][ki] = *(const bf16x8*)&qp[(nj * 16 + lo) * DH + ki * 32 + quad * 8];

  const unsigned short* kp = kb + (size_t)bh * LL * DH;
  const unsigned short* vp = vt + (size_t)bh * DH * LL;
  const float* ap = adj + ((size_t)b * LL + q0) * LL;
  const float* dp = dis + ((size_t)b * LL + q0) * LL;
  const float* mp = mad + b * LL;

  f32x4 o[4][2];  // O^T acc: [d-chunk][q-chunk]
  float rs[2] = {0.0f, 0.0f};
#pragma unroll
  for (int md = 0; md < 4; ++md)
#pragma unroll
    for (int nj = 0; nj < 2; ++nj) o[md][nj] = (f32x4)0.0f;

  const int kbeg = kh * (LL / 2);
  const int kend = kbeg + (LL / 2);

  // ---- preload pipeline stage for k0 = kbeg ----
  bf16x8 kA[2][2];
  f32x4 av[2][2], dv[2][2], mav[2];
#pragma unroll
  for (int mi = 0; mi < 2; ++mi)
#pragma unroll
    for (int ki = 0; ki < 2; ++ki)
      kA[mi][ki] = *(const bf16x8*)&kp[(kbeg + mi * 16 + lo) * DH + ki * 32 + quad * 8];
#pragma unroll
  for (int mi = 0; mi < 2; ++mi) {
#pragma unroll
    for (int nj = 0; nj < 2; ++nj) {
      av[mi][nj] = *(const f32x4*)&ap[(size_t)(nj * 16 + lo) * LL + kbeg + mi * 16 + quad * 4];
      dv[mi][nj] = *(const f32x4*)&dp[(size_t)(nj * 16 + lo) * LL + kbeg + mi * 16 + quad * 4];
    }
    mav[mi] = *(const f32x4*)&mp[kbeg + mi * 16 + quad * 4];
  }

  for (int k0 = kbeg; k0 < kend; k0 += 32) {
    const int kn = (k0 + 32 < kend) ? k0 + 32 : kbeg;  // safe redundant tail

    // V^T fragments for CURRENT iter (consumed at end -> long lead)
    bf16x8 vA[4];
#pragma unroll
    for (int md = 0; md < 4; ++md)
      vA[md] = *(const bf16x8*)&vp[(md * 16 + lo) * LL + k0 + quad * 8];

    // S^T = K Q^T (consumes kA)
    f32x4 s[2][2];
#pragma unroll
    for (int mi = 0; mi < 2; ++mi)
#pragma unroll
      for (int nj = 0; nj < 2; ++nj) s[mi][nj] = (f32x4)0.0f;
#pragma unroll
    for (int ki = 0; ki < 2; ++ki)
#pragma unroll
      for (int mi = 0; mi < 2; ++mi)
#pragma unroll
        for (int nj = 0; nj < 2; ++nj)
          s[mi][nj] = __builtin_amdgcn_mfma_f32_16x16x32_bf16(
              kA[mi][ki], qB[nj][ki], s[mi][nj], 0, 0, 0);

    // rotate: kA <- next iter (hidden behind exp + PV below)
#pragma unroll
    for (int mi = 0; mi < 2; ++mi)
#pragma unroll
      for (int ki = 0; ki < 2; ++ki)
        kA[mi][ki] = *(const bf16x8*)&kp[(kn + mi * 16 + lo) * DH + ki * 32 + quad * 8];

    // bias + mask + exp2, pack P^T pairs, 4x ds_write_b64
#pragma unroll
    for (int mi = 0; mi < 2; ++mi)
#pragma unroll
      for (int nj = 0; nj < 2; ++nj) {
        float p[4];
#pragma unroll
        for (int r = 0; r < 4; ++r) {
          float tt = fmaf(ld2, dv[mi][nj][r], mav[mi][r]);
          tt = fmaf(la2, av[mi][nj][r], tt);
          p[r] = __builtin_amdgcn_exp2f(fmaf(s[mi][nj][r], sc2, tt));
        }
        rs[nj] += (p[0] + p[1]) + (p[2] + p[3]);
        uint2 w = { pk2(p[0], p[1]), pk2(p[2], p[3]) };
        *(uint2*)&pbuf[wid][(nj * 16 + lo) * 40 + mi * 16 + quad * 4] = w;
      }

    // rotate: bias/mask <- next iter
#pragma unroll
    for (int mi = 0; mi < 2; ++mi) {
#pragma unroll
      for (int nj = 0; nj < 2; ++nj) {
        av[mi][nj] = *(const f32x4*)&ap[(size_t)(nj * 16 + lo) * LL + kn + mi * 16 + quad * 4];
        dv[mi][nj] = *(const f32x4*)&dp[(size_t)(nj * 16 + lo) * LL + kn + mi * 16 + quad * 4];
      }
      mav[mi] = *(const f32x4*)&mp[kn + mi * 16 + quad * 4];
    }

    // per-wave LDS write->read drain (lgkm only; globals keep flying)
    asm volatile("s_waitcnt lgkmcnt(0)" ::: "memory");

    bf16x8 pB[2];
#pragma unroll
    for (int nj = 0; nj < 2; ++nj)
      pB[nj] = *(const bf16x8*)&pbuf[wid][(nj * 16 + lo) * 40 + quad * 8];

    // O^T += V^T P (consumes vA)
#pragma unroll
    for (int md = 0; md < 4; ++md)
#pragma unroll
      for (int nj = 0; nj < 2; ++nj)
        o[md][nj] = __builtin_amdgcn_mfma_f32_16x16x32_bf16(
            vA[md], pB[nj], o[md][nj], 0, 0, 0);
  }

  // merge the two K-halves (unnormalized partials just add)
  const int hs = wid & 1;
  if (kh == 1) {
#pragma unroll
    for (int md = 0; md < 4; ++md)
#pragma unroll
      for (int nj = 0; nj < 2; ++nj)
#pragma unroll
        for (int r = 0; r < 4; ++r)
          mbuf[hs][((md * 2 + nj) * 4 + r) * 64 + lane] = o[md][nj][r];
    mbuf[hs][32 * 64 + lane] = rs[0];
    mbuf[hs][33 * 64 + lane] = rs[1];
  }
  __syncthreads();
  if (kh == 0) {
#pragma unroll
    for (int md = 0; md < 4; ++md)
#pragma unroll
      for (int nj = 0; nj < 2; ++nj)
#pragma unroll
        for (int r = 0; r < 4; ++r)
          o[md][nj][r] += mbuf[hs][((md * 2 + nj) * 4 + r) * 64 + lane];
    rs[0] += mbuf[hs][32 * 64 + lane];
    rs[1] += mbuf[hs][33 * 64 + lane];
    float inv[2];
#pragma unroll
    for (int nj = 0; nj < 2; ++nj) {
      rs[nj] += __shfl_xor(rs[nj], 16);
      rs[nj] += __shfl_xor(rs[nj], 32);
      inv[nj] = __builtin_amdgcn_rcpf(rs[nj]);
    }
#pragma unroll
    for (int md = 0; md < 4; ++md)
#pragma unroll
      for (int nj = 0; nj < 2; ++nj) {
        int l = q0 + nj * 16 + lo;
        uint2 st = { pk2(o[md][nj][0] * inv[nj], o[md][nj][1] * inv[nj]),
                     pk2(o[md][nj][2] * inv[nj], o[md][nj][3] * inv[nj]) };
        *(uint2*)&ao[((size_t)b * LL + l) * DM + h * DH + md * 16 + quad * 4] = st;
      }
  }
}

// ---------------- K3: output projection ----------------
// grid (8 ntile, 64 mtile), block 256
__global__ __launch_bounds__(256) void oproj(
    const unsigned short* __restrict__ ao, const unsigned short* __restrict__ wob,
    float* __restrict__ out)
{
  const int m0 = blockIdx.y * 128;
  const int n0 = blockIdx.x * 64;
  __shared__ unsigned short As[128 * 40];
  __shared__ unsigned short Bs[64 * 40];
  const int tid = threadIdx.x;
  const int wid = tid >> 6;
  const int lane = tid & 63;
  const int lo = lane & 15;
  const int quad = lane >> 4;

  f32x4 acc[2][4];
#pragma unroll
  for (int mi = 0; mi < 2; ++mi)
#pragma unroll
    for (int ni = 0; ni < 4; ++ni) acc[mi][ni] = (f32x4)0.0f;

  for (int kk = 0; kk < DM; kk += 32) {
#pragma unroll
    for (int i = 0; i < 2; ++i) {
      int id = i * 256 + tid;
      int row = id >> 2, ch = id & 3;
      *(uint4*)&As[row * 40 + ch * 8] =
          *(const uint4*)&ao[(size_t)(m0 + row) * DM + kk + ch * 8];
    }
    {
      int row = tid >> 2, ch = tid & 3;
      *(uint4*)&Bs[row * 40 + ch * 8] =
          *(const uint4*)&wob[(size_t)(n0 + row) * DM + kk + ch * 8];
    }
    __syncthreads();
    bf16x8 a[2], bfr[4];
#pragma unroll
    for (int mi = 0; mi < 2; ++mi)
      a[mi] = *(const bf16x8*)&As[(wid * 32 + mi * 16 + lo) * 40 + quad * 8];
#pragma unroll
    for (int ni = 0; ni < 4; ++ni)
      bfr[ni] = *(const bf16x8*)&Bs[(ni * 16 + lo) * 40 + quad * 8];
#pragma unroll
    for (int mi = 0; mi < 2; ++mi)
#pragma unroll
      for (int ni = 0; ni < 4; ++ni)
        acc[mi][ni] = __builtin_amdgcn_mfma_f32_16x16x32_bf16(
            a[mi], bfr[ni], acc[mi][ni], 0, 0, 0);
    __syncthreads();
  }

#pragma unroll
  for (int mi = 0; mi < 2; ++mi)
#pragma unroll
    for (int ni = 0; ni < 4; ++ni)
#pragma unroll
      for (int r = 0; r < 4; ++r)
        out[(size_t)(m0 + wid * 32 + mi * 16 + quad * 4 + r) * DM +
            n0 + ni * 16 + lo] = acc[mi][ni][r];
}

extern "C" void kernel_launch(void* const* d_in, const int* in_sizes, int n_in,
                              void* d_out, int out_size, void* d_ws, size_t ws_size,
                              hipStream_t stream) {
  const float* qin = (const float*)d_in[0];
  const float* kin = (const float*)d_in[1];
  const float* vin = (const float*)d_in[2];
  const int*   msk = (const int*)d_in[3];
  const float* adj = (const float*)d_in[4];
  const float* dis = (const float*)d_in[5];
  const float* wq  = (const float*)d_in[6];
  const float* wk  = (const float*)d_in[7];
  const float* wv  = (const float*)d_in[8];
  const float* wo  = (const float*)d_in[9];
  const float* la  = (const float*)d_in[10];
  const float* ld  = (const float*)d_in[11];
  float* out = (float*)d_out;

  const size_t tensb = (size_t)BB * HH * LL * DH;   // 4,194,304
  const size_t xsz   = (size_t)BB * LL * DIN;       // 2,097,152
  unsigned short* qb  = (unsigned short*)d_ws;
  unsigned short* kb  = qb + tensb;
  unsigned short* vt  = kb + tensb;
  unsigned short* ao  = vt + tensb;                 // (B,L,512) bf16
  // xq/xk alias ao (dead until attn writes it); xv + weights appended
  unsigned short* xq  = ao;
  unsigned short* xk  = ao + xsz;
  unsigned short* xv  = ao + tensb;
  unsigned short* wqb = xv + xsz;
  unsigned short* wkb = wqb + (size_t)DM * DIN;
  unsigned short* wvb = wkb + (size_t)DM * DIN;
  unsigned short* wob = wvb + (size_t)DM * DIN;
  float*          mdd = (float*)(wob + (size_t)DM * DM);

  prep<<<dim3(6792), 256, 0, stream>>>(qin, kin, vin, wq, wk, wv, wo, msk,
                                       xq, xk, xv, wqb, wkb, wvb, wob, mdd);
  qkv_proj<<<dim3(8, 64, 3), 256, 0, stream>>>(xq, xk, xv, wqb, wkb, wvb, qb, kb, vt);
  attn<<<dim3(1024), 256, 0, stream>>>(qb, kb, vt, mdd, adj, dis, la, ld, ao);
  oproj<<<dim3(8, 64), 256, 0, stream>>>(ao, wob, out);
}